// Round 8
// baseline (5195.264 us; speedup 1.0000x reference)
//
#include <hip/hip_runtime.h>
#include <hip/hip_cooperative_groups.h>
#include <math.h>

#define NB 4
#define L0 8192
#define CR 32
#define CD 32
#define CS 512
#define CE 256
#define NV 256
#define OUT_T 5632
#define XSTRIDE 8192
#define NL 50
#define KCAT 1600   // 50 * 32

typedef __attribute__((ext_vector_type(8))) short  short8;
typedef __attribute__((ext_vector_type(4))) float  f32x4;
typedef __attribute__((ext_vector_type(4))) float  f4;
typedef __attribute__((ext_vector_type(4))) unsigned short us4;

struct Sched { int T_out[NL]; int d[NL]; int P[NL]; };

static __device__ __forceinline__ unsigned short f2bf(float f) {
    unsigned int u = __builtin_bit_cast(unsigned int, f);
    u = (u + 0x7FFFu + ((u >> 16) & 1u)) >> 16;
    return (unsigned short)u;
}

// ---------------- Kernel P: weight f32 -> bf16 prep ----------------
__global__ __launch_bounds__(256) void k_prep(const float* __restrict__ sw,
                                              const float* __restrict__ w1,
                                              const float* __restrict__ w2,
                                              unsigned short* __restrict__ wsb,
                                              unsigned short* __restrict__ w1b,
                                              unsigned short* __restrict__ w2b)
{
    int idx = blockIdx.x * 256 + threadIdx.x;
    if (idx < NL * CS * CD) {
        int l = idx >> 14;
        int co = (idx >> 5) & 511;
        int c = idx & 31;
        wsb[co * KCAT + l * 32 + c] = f2bf(sw[idx]);
    } else if (idx < NL * CS * CD + CE * CS) {
        int e = idx - NL * CS * CD;
        w1b[e] = f2bf(w1[e]);
    } else {
        int e = idx - NL * CS * CD - CE * CS;
        w2b[e] = f2bf(w2[e]);
    }
}

// ---------------- Kernel A: embedding + causal pre-conv (k=2) ----------------
__global__ __launch_bounds__(256) void k_pre(const int* __restrict__ tokens,
                                             const float* __restrict__ emb,
                                             const float* __restrict__ pw,
                                             float* __restrict__ x)
{
    int idx = blockIdx.x * 256 + threadIdx.x;
    int t = idx & (L0 - 1);
    int o = (idx >> 13) & 31;
    int b = idx >> 18;
    const int* tb = tokens + b * L0;
    const float* e1 = emb + tb[t] * CR;
    const float* w = pw + o * CR * 2;
    float acc = 0.f;
    if (t > 0) {
        const float* e0 = emb + tb[t - 1] * CR;
#pragma unroll
        for (int i = 0; i < CR; ++i)
            acc += w[i * 2] * e0[i] + w[i * 2 + 1] * e1[i];
    } else {
#pragma unroll
        for (int i = 0; i < CR; ++i)
            acc += w[i * 2 + 1] * e1[i];
    }
    x[(b * CR + o) * XSTRIDE + t] = acc;
}

// ---------------- shared per-layer tile body ----------------
struct LayerSmem {
    float As[32][68];
    float Bs[32][68];
    float Zs[32][68];
    unsigned short ZsT[64][32];
    float wfT[64][33];
    float wgT[64][33];
    float rwT[32][33];
};

static __device__ __forceinline__ void layer_tile(
    LayerSmem& sm, int tid, int b, int t0,
    const float* __restrict__ x_in, float* __restrict__ x_out,
    unsigned short* __restrict__ Zt,
    const float* __restrict__ fw, const float* __restrict__ gw,
    const float* __restrict__ rw,
    int T_out, int d, int P, int skipOff, int kOff)
{
    const float* xb = x_in + b * CR * XSTRIDE;
    // stage weights transposed (inner index = out-channel)
    for (int e = tid; e < 2048; e += 256) {
        int c = e >> 6, i2 = e & 63;
        sm.wfT[i2][c] = fw[e];
        sm.wgT[i2][c] = gw[e];
    }
    for (int e = tid; e < 1024; e += 256) {
        int c = e >> 5, i = e & 31;
        sm.rwT[i][c] = rw[e];
    }
    // load x tiles: A = xin(t), B = xin(t+d), front-pad P zeros
    {
        int ch = tid >> 3;
        int j0 = (tid & 7) * 8;
        const float* row = xb + ch * XSTRIDE;
#pragma unroll
        for (int k = 0; k < 8; ++k) {
            int t = t0 + j0 + k;
            float a = 0.f, bb = 0.f;
            if (t < T_out) {
                if (t >= P) a = row[t - P];
                bb = row[t + d - P];
            }
            sm.As[ch][j0 + k] = a;
            sm.Bs[ch][j0 + k] = bb;
        }
    }
    __syncthreads();
    // gated activation
    {
        int c = tid & 31;
        int j0 = (tid >> 5) * 8;
        float af[8] = {0, 0, 0, 0, 0, 0, 0, 0};
        float ag[8] = {0, 0, 0, 0, 0, 0, 0, 0};
#pragma unroll
        for (int i = 0; i < 32; ++i) {
            float av[8], bv[8];
            *(f4*)&av[0] = *(const f4*)&sm.As[i][j0];
            *(f4*)&av[4] = *(const f4*)&sm.As[i][j0 + 4];
            *(f4*)&bv[0] = *(const f4*)&sm.Bs[i][j0];
            *(f4*)&bv[4] = *(const f4*)&sm.Bs[i][j0 + 4];
            float f0 = sm.wfT[2 * i][c], f1 = sm.wfT[2 * i + 1][c];
            float g0 = sm.wgT[2 * i][c], g1 = sm.wgT[2 * i + 1][c];
#pragma unroll
            for (int k = 0; k < 8; ++k) {
                af[k] += f0 * av[k] + f1 * bv[k];
                ag[k] += g0 * av[k] + g1 * bv[k];
            }
        }
#pragma unroll
        for (int k = 0; k < 8; ++k) {
            float e2a = __expf(2.f * af[k]);
            float th = 1.f - __fdividef(2.f, e2a + 1.f);
            float sg = __fdividef(1.f, 1.f + __expf(-ag[k]));
            float z = th * sg;
            sm.Zs[c][j0 + k] = z;
            sm.ZsT[j0 + k][c] = f2bf(z);
        }
    }
    __syncthreads();
    // residual: x_out = Wr z + xin(t+d)
    {
        int ch = tid >> 3;
        int j0 = (tid & 7) * 8;
        float accv[8];
        *(f4*)&accv[0] = *(const f4*)&sm.Bs[ch][j0];
        *(f4*)&accv[4] = *(const f4*)&sm.Bs[ch][j0 + 4];
#pragma unroll
        for (int i = 0; i < 32; ++i) {
            float w = sm.rwT[i][ch];
            float zv[8];
            *(f4*)&zv[0] = *(const f4*)&sm.Zs[i][j0];
            *(f4*)&zv[4] = *(const f4*)&sm.Zs[i][j0 + 4];
#pragma unroll
            for (int k = 0; k < 8; ++k)
                accv[k] += w * zv[k];
        }
        float* orow = x_out + (b * CR + ch) * XSTRIDE;
#pragma unroll
        for (int k = 0; k < 8; ++k) {
            int t = t0 + j0 + k;
            if (t < T_out) orow[t] = accv[k];
        }
    }
    // Zt write-out (channel-contiguous bf16, trailing OUT_T window)
    {
        int tl = tid >> 2;
        int cq = (tid & 3) * 8;
        int t = t0 + tl;
        if (t >= skipOff && t < T_out) {
            unsigned short* dst =
                Zt + ((size_t)b * OUT_T + (t - skipOff)) * KCAT + kOff + cq;
            *(short8*)dst = *(const short8*)&sm.ZsT[tl][cq];
        }
    }
}

// ---------------- Fused persistent kernel: embed+pre conv + 50 layers ----------------
__global__ __launch_bounds__(256, 2) void k_fused(
    const int* __restrict__ tokens, const float* __restrict__ emb,
    const float* __restrict__ pre_w,
    const float* __restrict__ filt_w, const float* __restrict__ gate_w,
    const float* __restrict__ res_w,
    float* __restrict__ xA, float* __restrict__ xB,
    unsigned short* __restrict__ Zt, Sched s)
{
    cooperative_groups::grid_group grid = cooperative_groups::this_grid();
    const int tid = threadIdx.x;
    __shared__ LayerSmem sm;

    // ---- phase 0: embedding + causal pre-conv (k=2) -> xA ----
    for (int idx = blockIdx.x * 256 + tid; idx < NB * CR * L0; idx += gridDim.x * 256) {
        int t = idx & (L0 - 1);
        int o = (idx >> 13) & 31;
        int b = idx >> 18;
        const int* tb = tokens + b * L0;
        const float* e1 = emb + tb[t] * CR;
        const float* w = pre_w + o * CR * 2;
        float acc = 0.f;
        if (t > 0) {
            const float* e0 = emb + tb[t - 1] * CR;
#pragma unroll
            for (int i = 0; i < CR; ++i)
                acc += w[i * 2] * e0[i] + w[i * 2 + 1] * e1[i];
        } else {
#pragma unroll
            for (int i = 0; i < CR; ++i)
                acc += w[i * 2 + 1] * e1[i];
        }
        xA[(b * CR + o) * XSTRIDE + t] = acc;
    }
    grid.sync();

    // ---- phases 1..50: dilated gated layers ----
    for (int li = 0; li < NL; ++li) {
        const float* x_in = (li & 1) ? xB : xA;
        float* x_out = (li & 1) ? xA : xB;
        const int T_out = s.T_out[li];
        const int ntiles = (T_out + 63) >> 6;
        if ((int)blockIdx.x < ntiles * NB) {
            const int b = blockIdx.x / ntiles;
            const int t0 = (blockIdx.x - b * ntiles) * 64;
            layer_tile(sm, tid, b, t0, x_in, x_out, Zt,
                       filt_w + (size_t)li * CD * CR * 2,
                       gate_w + (size_t)li * CD * CR * 2,
                       res_w + (size_t)li * CR * CD,
                       T_out, s.d[li], s.P[li], T_out - OUT_T, li * 32);
        }
        grid.sync();
    }
}

// ---------------- Fallback: one layer per launch (round-3 structure) ----------------
__global__ __launch_bounds__(256) void k_layer(
    const float* __restrict__ x_in, float* __restrict__ x_out,
    unsigned short* __restrict__ Zt,
    const float* __restrict__ fw, const float* __restrict__ gw,
    const float* __restrict__ rw,
    int T_out, int d, int P, int skipOff, int kOff)
{
    __shared__ LayerSmem sm;
    layer_tile(sm, threadIdx.x, blockIdx.y, blockIdx.x * 64,
               x_in, x_out, Zt, fw, gw, rw, T_out, d, P, skipOff, kOff);
}

// ---------------- MFMA GEMM: C[b] = A * B[b]^T(+bias)(+relu) ----------------
template <int MODE>
__global__ __launch_bounds__(256) void k_gemm(
    const unsigned short* __restrict__ A,
    const unsigned short* __restrict__ B,
    const float* __restrict__ bias,
    void* __restrict__ Cout, int M, int K)
{
    __shared__ unsigned short Asm[128][72];
    __shared__ unsigned short Bsm[64][72];
    const int tid = threadIdx.x;
    const int n0 = blockIdx.x * 64;
    const int m0 = blockIdx.y * 128;
    const int b = blockIdx.z;
    const unsigned short* Bb = B + (size_t)b * OUT_T * K;
    const int lane = tid & 63;
    const int wm = tid >> 6;
    f32x4 acc[2][4];
#pragma unroll
    for (int fm = 0; fm < 2; ++fm)
#pragma unroll
        for (int fn = 0; fn < 4; ++fn)
            acc[fm][fn] = (f32x4){0.f, 0.f, 0.f, 0.f};

    for (int kb = 0; kb < K; kb += 64) {
        __syncthreads();
#pragma unroll
        for (int it = 0; it < 4; ++it) {
            int lin = tid + it * 256;
            int row = lin >> 3, c8 = (lin & 7) * 8;
            *(short8*)&Asm[row][c8] =
                *(const short8*)&A[(size_t)(m0 + row) * K + kb + c8];
        }
#pragma unroll
        for (int it = 0; it < 2; ++it) {
            int lin = tid + it * 256;
            int row = lin >> 3, c8 = (lin & 7) * 8;
            *(short8*)&Bsm[row][c8] =
                *(const short8*)&Bb[(size_t)(n0 + row) * K + kb + c8];
        }
        __syncthreads();
#pragma unroll
        for (int kk = 0; kk < 2; ++kk) {
            short8 a[2], bb[4];
#pragma unroll
            for (int fm = 0; fm < 2; ++fm)
                a[fm] = *(const short8*)&Asm[wm * 32 + fm * 16 + (lane & 15)]
                                           [kk * 32 + (lane >> 4) * 8];
#pragma unroll
            for (int fn = 0; fn < 4; ++fn)
                bb[fn] = *(const short8*)&Bsm[fn * 16 + (lane & 15)]
                                            [kk * 32 + (lane >> 4) * 8];
#pragma unroll
            for (int fm = 0; fm < 2; ++fm)
#pragma unroll
                for (int fn = 0; fn < 4; ++fn)
                    acc[fm][fn] = __builtin_amdgcn_mfma_f32_16x16x32_bf16(
                        a[fm], bb[fn], acc[fm][fn], 0, 0, 0);
        }
    }
#pragma unroll
    for (int fm = 0; fm < 2; ++fm) {
        int mb = m0 + wm * 32 + fm * 16 + (lane >> 4) * 4;
#pragma unroll
        for (int fn = 0; fn < 4; ++fn) {
            int n = n0 + fn * 16 + (lane & 15);
            float v[4];
#pragma unroll
            for (int r = 0; r < 4; ++r) {
                v[r] = acc[fm][fn][r];
                if (MODE >= 1) v[r] += bias[mb + r];
                if (MODE <= 1) v[r] = v[r] > 0.f ? v[r] : 0.f;
            }
            if (MODE == 2) {
                float* o = (float*)Cout;
#pragma unroll
                for (int r = 0; r < 4; ++r)
                    o[((size_t)b * NV + mb + r) * OUT_T + n] = v[r];
            } else {
                unsigned short* o = (unsigned short*)Cout;
                us4 pk;
#pragma unroll
                for (int r = 0; r < 4; ++r) pk[r] = f2bf(v[r]);
                *(us4*)&o[((size_t)b * OUT_T + n) * M + mb] = pk;
            }
        }
    }
}

extern "C" void kernel_launch(void* const* d_in, const int* in_sizes, int n_in,
                              void* d_out, int out_size, void* d_ws, size_t ws_size,
                              hipStream_t stream)
{
    const int*   tokens  = (const int*)d_in[0];
    const float* emb     = (const float*)d_in[1];
    const float* pre_w   = (const float*)d_in[2];
    const float* filt_w  = (const float*)d_in[3];
    const float* gate_w  = (const float*)d_in[4];
    const float* res_w   = (const float*)d_in[5];
    const float* skip_w  = (const float*)d_in[6];
    const float* post_w1 = (const float*)d_in[7];
    const float* post_b1 = (const float*)d_in[8];
    const float* post_w2 = (const float*)d_in[9];
    const float* post_b2 = (const float*)d_in[10];
    float* out = (float*)d_out;

    char* ws = (char*)d_ws;
    float* xA = (float*)ws;                 ws += (size_t)NB * CR * XSTRIDE * 4;
    float* xB = (float*)ws;                 ws += (size_t)NB * CR * XSTRIDE * 4;
    unsigned short* Zt    = (unsigned short*)ws; ws += (size_t)NB * OUT_T * KCAT * 2;
    unsigned short* skipT = (unsigned short*)ws; ws += (size_t)NB * OUT_T * CS * 2;
    unsigned short* h1T   = (unsigned short*)ws; ws += (size_t)NB * OUT_T * CE * 2;
    unsigned short* wsb   = (unsigned short*)ws; ws += (size_t)CS * KCAT * 2;
    unsigned short* w1b   = (unsigned short*)ws; ws += (size_t)CE * CS * 2;
    unsigned short* w2b   = (unsigned short*)ws; ws += (size_t)NV * CE * 2;

    k_prep<<<3968, 256, 0, stream>>>(skip_w, post_w1, post_w2, wsb, w1b, w2b);

    // static layer schedule (mirrors reference dilate() padding)
    Sched s;
    {
        int T = L0, init = 1, li = 0;
        for (int blk = 0; blk < 5; ++blk) {
            int nw = 1;
            for (int j = 0; j < 10; ++j) {
                int d = nw, P = 0;
                if (d > init) {
                    int r = d / init;
                    int l = T / init;
                    int nl = ((l + r - 1) / r) * r;
                    P = (nl - l) * init;
                }
                int T_out = T + P - d;
                s.T_out[li] = T_out; s.d[li] = d; s.P[li] = P;
                T = T_out; init = d; nw <<= 1; ++li;
            }
        }
    }

    const int* tk = tokens;
    void* args[] = {(void*)&tk, (void*)&emb, (void*)&pre_w,
                    (void*)&filt_w, (void*)&gate_w, (void*)&res_w,
                    (void*)&xA, (void*)&xB, (void*)&Zt, (void*)&s};
    hipError_t cerr = hipLaunchCooperativeKernel((const void*)k_fused, dim3(512),
                                                 dim3(256), args, 0, stream);
    if (cerr != hipSuccess) {
        // Fallback: per-layer launches (round-3 structure, measured-correct).
        k_pre<<<(NB * CR * L0) / 256, 256, 0, stream>>>(tokens, emb, pre_w, xA);
        float* xin = xA; float* xout = xB;
        for (int li = 0; li < NL; ++li) {
            int T_out = s.T_out[li];
            dim3 grid((T_out + 63) / 64, NB);
            k_layer<<<grid, 256, 0, stream>>>(
                xin, xout, Zt,
                filt_w + (size_t)li * CD * CR * 2,
                gate_w + (size_t)li * CD * CR * 2,
                res_w + (size_t)li * CR * CD,
                T_out, s.d[li], s.P[li], T_out - OUT_T, li * 32);
            float* tmp = xin; xin = xout; xout = tmp;
        }
    }

    dim3 gs(OUT_T / 64, CS / 128, NB);
    k_gemm<0><<<gs, 256, 0, stream>>>(wsb, Zt, nullptr, skipT, CS, KCAT);
    dim3 g1(OUT_T / 64, CE / 128, NB);
    k_gemm<1><<<g1, 256, 0, stream>>>(w1b, skipT, post_b1, h1T, CE, CS);
    dim3 g2(OUT_T / 64, NV / 128, NB);
    k_gemm<2><<<g2, 256, 0, stream>>>(w2b, h1T, post_b2, out, NV, CE);
}

// Round 9
// 1642.166 us; speedup vs baseline: 3.1637x; 3.1637x over previous
//
#include <hip/hip_runtime.h>
#include <math.h>

#define NB 4
#define L0 8192
#define CR 32
#define CD 32
#define CS 512
#define CE 256
#define NV 256
#define OUT_T 5632
#define XSTRIDE 8192
#define NL 50
#define KCAT 1600   // 50 * 32
#define TW 128      // pair-kernel tile width

typedef __attribute__((ext_vector_type(8))) short  short8;
typedef __attribute__((ext_vector_type(4))) float  f32x4;
typedef __attribute__((ext_vector_type(4))) float  f4;
typedef __attribute__((ext_vector_type(4))) unsigned short us4;

static __device__ __forceinline__ unsigned short f2bf(float f) {
    unsigned int u = __builtin_bit_cast(unsigned int, f);
    u = (u + 0x7FFFu + ((u >> 16) & 1u)) >> 16;
    return (unsigned short)u;
}

// ---------------- Kernel P: weight f32 -> bf16 prep ----------------
__global__ __launch_bounds__(256) void k_prep(const float* __restrict__ sw,
                                              const float* __restrict__ w1,
                                              const float* __restrict__ w2,
                                              unsigned short* __restrict__ wsb,
                                              unsigned short* __restrict__ w1b,
                                              unsigned short* __restrict__ w2b)
{
    int idx = blockIdx.x * 256 + threadIdx.x;
    if (idx < NL * CS * CD) {
        int l = idx >> 14;
        int co = (idx >> 5) & 511;
        int c = idx & 31;
        wsb[co * KCAT + l * 32 + c] = f2bf(sw[idx]);
    } else if (idx < NL * CS * CD + CE * CS) {
        int e = idx - NL * CS * CD;
        w1b[e] = f2bf(w1[e]);
    } else {
        int e = idx - NL * CS * CD - CE * CS;
        w2b[e] = f2bf(w2[e]);
    }
}

// ---------------- Kernel A: embedding + causal pre-conv (k=2) ----------------
__global__ __launch_bounds__(256) void k_pre(const int* __restrict__ tokens,
                                             const float* __restrict__ emb,
                                             const float* __restrict__ pw,
                                             float* __restrict__ x)
{
    int idx = blockIdx.x * 256 + threadIdx.x;
    int t = idx & (L0 - 1);
    int o = (idx >> 13) & 31;
    int b = idx >> 18;
    const int* tb = tokens + b * L0;
    const float* e1 = emb + tb[t] * CR;
    const float* w = pw + o * CR * 2;
    float acc = 0.f;
    if (t > 0) {
        const float* e0 = emb + tb[t - 1] * CR;
#pragma unroll
        for (int i = 0; i < CR; ++i)
            acc += w[i * 2] * e0[i] + w[i * 2 + 1] * e1[i];
    } else {
#pragma unroll
        for (int i = 0; i < CR; ++i)
            acc += w[i * 2 + 1] * e1[i];
    }
    x[(b * CR + o) * XSTRIDE + t] = acc;
}

// ---------------- Pair kernel LDS ----------------
struct PairSmem {
    float T00[32][136];   // x1in(baseA + j)
    float T01[32][136];   // x1in(baseA + d1 + j)
    float T10[32][136];   // x1in(baseB + j)
    float T11[32][136];   // x1in(baseB + d1 + j)
    float ZA[32][136];
    float ZB[32][136];
    float wfT[64][33];
    float wgT[64][33];
    float rwT[32][33];
    unsigned short ZsT[2][128][32];
};
static_assert(sizeof(PairSmem) <= 160 * 1024, "LDS overflow");

// gated activation on a 32x128 tile pair (X0 = tap0, X1 = tap1)
static __device__ __forceinline__ void gate_tile(
    const float (*__restrict__ X0)[136], const float (*__restrict__ X1)[136],
    float (*__restrict__ Zf)[136], unsigned short (*__restrict__ Zb)[32],
    const float (*__restrict__ wf)[33], const float (*__restrict__ wg)[33],
    int c, int j0)
{
    float af[8] = {0, 0, 0, 0, 0, 0, 0, 0};
    float ag[8] = {0, 0, 0, 0, 0, 0, 0, 0};
#pragma unroll
    for (int i = 0; i < 32; ++i) {
        float av[8], bv[8];
        *(f4*)&av[0] = *(const f4*)&X0[i][j0];
        *(f4*)&av[4] = *(const f4*)&X0[i][j0 + 4];
        *(f4*)&bv[0] = *(const f4*)&X1[i][j0];
        *(f4*)&bv[4] = *(const f4*)&X1[i][j0 + 4];
        float f0 = wf[2 * i][c], f1 = wf[2 * i + 1][c];
        float g0 = wg[2 * i][c], g1 = wg[2 * i + 1][c];
#pragma unroll
        for (int k = 0; k < 8; ++k) {
            af[k] += f0 * av[k] + f1 * bv[k];
            ag[k] += g0 * av[k] + g1 * bv[k];
        }
    }
#pragma unroll
    for (int k = 0; k < 8; ++k) {
        float e2a = __expf(2.f * af[k]);
        float th = 1.f - __fdividef(2.f, e2a + 1.f);
        float sg = __fdividef(1.f, 1.f + __expf(-ag[k]));
        float z = th * sg;
        Zf[c][j0 + k] = z;
        Zb[j0 + k][c] = f2bf(z);
    }
}

// residual: out[k] = Xd[ch][j0+k] + sum_i rw[i][ch] * Zf[i][j0+k]
static __device__ __forceinline__ void resid_tile(
    const float (*__restrict__ Xd)[136], const float (*__restrict__ Zf)[136],
    const float (*__restrict__ rw)[33], float* __restrict__ out, int ch, int j0)
{
    *(f4*)&out[0] = *(const f4*)&Xd[ch][j0];
    *(f4*)&out[4] = *(const f4*)&Xd[ch][j0 + 4];
#pragma unroll
    for (int i = 0; i < 32; ++i) {
        float w = rw[i][ch];
        float zv[8];
        *(f4*)&zv[0] = *(const f4*)&Zf[i][j0];
        *(f4*)&zv[4] = *(const f4*)&Zf[i][j0 + 4];
#pragma unroll
        for (int k = 0; k < 8; ++k)
            out[k] += w * zv[k];
    }
}

// ---------------- Kernel B: TWO fused WaveNet layers (sparse 4-tap) ----------------
// layer1: z1[u]=act(Wf1_0 x1in(u)+Wf1_1 x1in(u+d1)); x1out[u]=Wr1 z1[u]+x1in(u+d1)
//         x1in(u) = (0<=u-P1<T0) ? x0[u-P1] : 0
// layer2: x2in(t) = (t<P2)?0:x1out[t-P2]; z2, x2out analogous.
// Block computes output tile t in [t0,t0+TW): needs x1out at A=t0-P2, B=t0+d2-P2.
// z1 skip rows written from BOTH A and B tiles (lattices jointly cover [0,T1);
// overlapping writes carry identical values).
__global__ __launch_bounds__(512, 1) void k_pair(
    const float* __restrict__ x0, float* __restrict__ x_out,
    unsigned short* __restrict__ Zt,
    const float* __restrict__ fw1, const float* __restrict__ gw1,
    const float* __restrict__ rw1,
    const float* __restrict__ fw2, const float* __restrict__ gw2,
    const float* __restrict__ rw2,
    int T0, int T1, int T2, int d1, int d2, int P1, int P2,
    int skip1, int skip2, int kOff1, int kOff2)
{
    extern __shared__ char smraw[];
    PairSmem& sm = *reinterpret_cast<PairSmem*>(smraw);
    const int tid = threadIdx.x;
    const int b = blockIdx.y;
    const int t0 = blockIdx.x * TW;
    const int baseA = t0 - P2;
    const int baseB = t0 + d2 - P2;

    // ---- P0: stage layer-1 weights (transposed) + load the 4 x1in tiles ----
    for (int e = tid; e < 2048; e += 512) {
        int c = e >> 6, i2 = e & 63;
        sm.wfT[i2][c] = fw1[e];
        sm.wgT[i2][c] = gw1[e];
    }
    for (int e = tid; e < 1024; e += 512)
        sm.rwT[e & 31][e >> 5] = rw1[e];
    {
        int ch = tid >> 4;
        int j0 = (tid & 15) * 8;
        const float* row = x0 + ((size_t)b * CR + ch) * XSTRIDE;
        const int bases[4] = {baseA, baseA + d1, baseB, baseB + d1};
        float* const dsts[4] = {&sm.T00[ch][j0], &sm.T01[ch][j0],
                                &sm.T10[ch][j0], &sm.T11[ch][j0]};
#pragma unroll
        for (int q = 0; q < 4; ++q) {
            int iu0 = bases[q] + j0 - P1;
            float v[8];
            if (iu0 >= 0 && iu0 + 7 < T0) {
#pragma unroll
                for (int k = 0; k < 8; ++k) v[k] = row[iu0 + k];
            } else {
#pragma unroll
                for (int k = 0; k < 8; ++k) {
                    int iu = iu0 + k;
                    v[k] = (iu >= 0 && iu < T0) ? row[iu] : 0.f;
                }
            }
#pragma unroll
            for (int k = 0; k < 8; ++k) dsts[q][k] = v[k];
        }
    }
    __syncthreads();

    // ---- P1: layer-1 gated activation for A and B tiles ----
    {
        int c = tid & 31;
        int j0 = (tid >> 5) * 8;
        gate_tile(sm.T00, sm.T01, sm.ZA, sm.ZsT[0], sm.wfT, sm.wgT, c, j0);
        gate_tile(sm.T10, sm.T11, sm.ZB, sm.ZsT[1], sm.wfT, sm.wgT, c, j0);
    }
    __syncthreads();

    // ---- P2: layer-1 Zt stores; x1out into T00/T10; stage layer-2 wf/wg ----
    for (int e = tid; e < 2048; e += 512) {   // wf/wg last read in P1 (pre-S2)
        int c = e >> 6, i2 = e & 63;
        sm.wfT[i2][c] = fw2[e];
        sm.wgT[i2][c] = gw2[e];
    }
#pragma unroll
    for (int s = 0; s < 2; ++s) {
        int lin = tid + s * 512;
        int tile = lin >> 9;
        int r = lin & 511;
        int j = r >> 2, cq = (r & 3) * 8;
        int u = (tile ? baseB : baseA) + j;
        if (u >= skip1 && u < T1) {
            unsigned short* dst =
                Zt + ((size_t)b * OUT_T + (u - skip1)) * KCAT + kOff1 + cq;
            *(short8*)dst = *(const short8*)&sm.ZsT[tile][j][cq];
        }
    }
    {
        int ch = tid >> 4;
        int j0 = (tid & 15) * 8;
        float acc[8];
        resid_tile(sm.T01, sm.ZA, sm.rwT, acc, ch, j0);
#pragma unroll
        for (int k = 0; k < 8; ++k)   // fold layer-2 front-pad: x2in(t<P2)=0
            sm.T00[ch][j0 + k] = (t0 + j0 + k >= P2) ? acc[k] : 0.f;
        resid_tile(sm.T11, sm.ZB, sm.rwT, acc, ch, j0);
#pragma unroll
        for (int k = 0; k < 8; ++k)
            sm.T10[ch][j0 + k] = acc[k];
    }
    __syncthreads();

    // ---- P3: layer-2 gated activation; stage rw2 ----
    for (int e = tid; e < 1024; e += 512)     // rw1 last read in P2 (pre-S3)
        sm.rwT[e & 31][e >> 5] = rw2[e];
    {
        int c = tid & 31;
        int j0 = (tid >> 5) * 8;
        gate_tile(sm.T00, sm.T10, sm.ZA, sm.ZsT[0], sm.wfT, sm.wgT, c, j0);
    }
    __syncthreads();

    // ---- P4: layer-2 Zt store + x2out ----
    {
        int j = tid >> 2, cq = (tid & 3) * 8;
        int t = t0 + j;
        if (t >= skip2 && t < T2) {
            unsigned short* dst =
                Zt + ((size_t)b * OUT_T + (t - skip2)) * KCAT + kOff2 + cq;
            *(short8*)dst = *(const short8*)&sm.ZsT[0][j][cq];
        }
    }
    {
        int ch = tid >> 4;
        int j0 = (tid & 15) * 8;
        float acc[8];
        resid_tile(sm.T10, sm.ZA, sm.rwT, acc, ch, j0);
        float* orow = x_out + ((size_t)b * CR + ch) * XSTRIDE;
#pragma unroll
        for (int k = 0; k < 8; ++k) {
            int t = t0 + j0 + k;
            if (t < T2) orow[t] = acc[k];
        }
    }
}

// ---------------- MFMA GEMM: C[b] = A * B[b]^T(+bias)(+relu) ----------------
template <int MODE>
__global__ __launch_bounds__(256) void k_gemm(
    const unsigned short* __restrict__ A,
    const unsigned short* __restrict__ B,
    const float* __restrict__ bias,
    void* __restrict__ Cout, int M, int K)
{
    __shared__ unsigned short Asm[128][72];
    __shared__ unsigned short Bsm[64][72];
    const int tid = threadIdx.x;
    const int n0 = blockIdx.x * 64;
    const int m0 = blockIdx.y * 128;
    const int b = blockIdx.z;
    const unsigned short* Bb = B + (size_t)b * OUT_T * K;
    const int lane = tid & 63;
    const int wm = tid >> 6;
    f32x4 acc[2][4];
#pragma unroll
    for (int fm = 0; fm < 2; ++fm)
#pragma unroll
        for (int fn = 0; fn < 4; ++fn)
            acc[fm][fn] = (f32x4){0.f, 0.f, 0.f, 0.f};

    for (int kb = 0; kb < K; kb += 64) {
        __syncthreads();
#pragma unroll
        for (int it = 0; it < 4; ++it) {
            int lin = tid + it * 256;
            int row = lin >> 3, c8 = (lin & 7) * 8;
            *(short8*)&Asm[row][c8] =
                *(const short8*)&A[(size_t)(m0 + row) * K + kb + c8];
        }
#pragma unroll
        for (int it = 0; it < 2; ++it) {
            int lin = tid + it * 256;
            int row = lin >> 3, c8 = (lin & 7) * 8;
            *(short8*)&Bsm[row][c8] =
                *(const short8*)&Bb[(size_t)(n0 + row) * K + kb + c8];
        }
        __syncthreads();
#pragma unroll
        for (int kk = 0; kk < 2; ++kk) {
            short8 a[2], bb[4];
#pragma unroll
            for (int fm = 0; fm < 2; ++fm)
                a[fm] = *(const short8*)&Asm[wm * 32 + fm * 16 + (lane & 15)]
                                           [kk * 32 + (lane >> 4) * 8];
#pragma unroll
            for (int fn = 0; fn < 4; ++fn)
                bb[fn] = *(const short8*)&Bsm[fn * 16 + (lane & 15)]
                                            [kk * 32 + (lane >> 4) * 8];
#pragma unroll
            for (int fm = 0; fm < 2; ++fm)
#pragma unroll
                for (int fn = 0; fn < 4; ++fn)
                    acc[fm][fn] = __builtin_amdgcn_mfma_f32_16x16x32_bf16(
                        a[fm], bb[fn], acc[fm][fn], 0, 0, 0);
        }
    }
#pragma unroll
    for (int fm = 0; fm < 2; ++fm) {
        int mb = m0 + wm * 32 + fm * 16 + (lane >> 4) * 4;
#pragma unroll
        for (int fn = 0; fn < 4; ++fn) {
            int n = n0 + fn * 16 + (lane & 15);
            float v[4];
#pragma unroll
            for (int r = 0; r < 4; ++r) {
                v[r] = acc[fm][fn][r];
                if (MODE >= 1) v[r] += bias[mb + r];
                if (MODE <= 1) v[r] = v[r] > 0.f ? v[r] : 0.f;
            }
            if (MODE == 2) {
                float* o = (float*)Cout;
#pragma unroll
                for (int r = 0; r < 4; ++r)
                    o[((size_t)b * NV + mb + r) * OUT_T + n] = v[r];
            } else {
                unsigned short* o = (unsigned short*)Cout;
                us4 pk;
#pragma unroll
                for (int r = 0; r < 4; ++r) pk[r] = f2bf(v[r]);
                *(us4*)&o[((size_t)b * OUT_T + n) * M + mb] = pk;
            }
        }
    }
}

extern "C" void kernel_launch(void* const* d_in, const int* in_sizes, int n_in,
                              void* d_out, int out_size, void* d_ws, size_t ws_size,
                              hipStream_t stream)
{
    const int*   tokens  = (const int*)d_in[0];
    const float* emb     = (const float*)d_in[1];
    const float* pre_w   = (const float*)d_in[2];
    const float* filt_w  = (const float*)d_in[3];
    const float* gate_w  = (const float*)d_in[4];
    const float* res_w   = (const float*)d_in[5];
    const float* skip_w  = (const float*)d_in[6];
    const float* post_w1 = (const float*)d_in[7];
    const float* post_b1 = (const float*)d_in[8];
    const float* post_w2 = (const float*)d_in[9];
    const float* post_b2 = (const float*)d_in[10];
    float* out = (float*)d_out;

    char* ws = (char*)d_ws;
    float* xA = (float*)ws;                 ws += (size_t)NB * CR * XSTRIDE * 4;
    float* xB = (float*)ws;                 ws += (size_t)NB * CR * XSTRIDE * 4;
    unsigned short* Zt    = (unsigned short*)ws; ws += (size_t)NB * OUT_T * KCAT * 2;
    unsigned short* skipT = (unsigned short*)ws; ws += (size_t)NB * OUT_T * CS * 2;
    unsigned short* h1T   = (unsigned short*)ws; ws += (size_t)NB * OUT_T * CE * 2;
    unsigned short* wsb   = (unsigned short*)ws; ws += (size_t)CS * KCAT * 2;
    unsigned short* w1b   = (unsigned short*)ws; ws += (size_t)CE * CS * 2;
    unsigned short* w2b   = (unsigned short*)ws; ws += (size_t)NV * CE * 2;

    k_prep<<<3968, 256, 0, stream>>>(skip_w, post_w1, post_w2, wsb, w1b, w2b);
    k_pre<<<(NB * CR * L0) / 256, 256, 0, stream>>>(tokens, emb, pre_w, xA);

    // static layer schedule (mirrors reference dilate() padding)
    int dArr[NL], pArr[NL], tArr[NL];
    {
        int T = L0, init = 1, li = 0;
        for (int blk = 0; blk < 5; ++blk) {
            int nw = 1;
            for (int j = 0; j < 10; ++j) {
                int d = nw, P = 0;
                if (d > init) {
                    int r = d / init;
                    int l = T / init;
                    int nl = ((l + r - 1) / r) * r;
                    P = (nl - l) * init;
                }
                int T_out = T + P - d;
                dArr[li] = d; pArr[li] = P; tArr[li] = T_out;
                T = T_out; init = d; nw <<= 1; ++li;
            }
        }
    }

    // 25 pair kernels (layers 2p, 2p+1 — pairs never cross a WaveNet block)
    float* xin = xA;
    float* xout = xB;
    for (int p = 0; p < 25; ++p) {
        int l1 = 2 * p, l2 = 2 * p + 1;
        int T0 = (l1 == 0) ? L0 : tArr[l1 - 1];
        int T1 = tArr[l1], T2 = tArr[l2];
        int ntiles = (T2 + TW - 1) / TW;
        dim3 grid(ntiles, NB);
        k_pair<<<grid, 512, sizeof(PairSmem), stream>>>(
            xin, xout, Zt,
            filt_w + (size_t)l1 * CD * CR * 2,
            gate_w + (size_t)l1 * CD * CR * 2,
            res_w + (size_t)l1 * CR * CD,
            filt_w + (size_t)l2 * CD * CR * 2,
            gate_w + (size_t)l2 * CD * CR * 2,
            res_w + (size_t)l2 * CR * CD,
            T0, T1, T2, dArr[l1], dArr[l2], pArr[l1], pArr[l2],
            T1 - OUT_T, T2 - OUT_T, l1 * 32, l2 * 32);
        float* tmp = xin; xin = xout; xout = tmp;
    }

    dim3 gs(OUT_T / 64, CS / 128, NB);
    k_gemm<0><<<gs, 256, 0, stream>>>(wsb, Zt, nullptr, skipT, CS, KCAT);
    dim3 g1(OUT_T / 64, CE / 128, NB);
    k_gemm<1><<<g1, 256, 0, stream>>>(w1b, skipT, post_b1, h1T, CE, CS);
    dim3 g2(OUT_T / 64, NV / 128, NB);
    k_gemm<2><<<g2, 256, 0, stream>>>(w2b, h1T, post_b2, out, NV, CE);
}